// Round 2
// baseline (321.088 us; speedup 1.0000x reference)
//
#include <hip/hip_runtime.h>
#include <math.h>

// Pool2d: 3x3 max pool, stride 2, pad 1 (fill 0.0), dilation 1.
// X: (32,192,224,224) f32 NCHW -> Y: (32,192,112,112) f32.
// Memory-bound: 1.233 GB in + 0.308 GB out => ~237-245 us floor @ 6.3-6.5 TB/s.
//
// R2: 2x8 output tile per thread-iter. Output rows (2p, 2p+1) share input row
// 4p+1 -> loaded once into registers (5 input rows per 2 output rows instead
// of 6), and ~21 loads issued per iter doubles MLP vs R1's 9.

namespace {
constexpr int H = 224;
constexpr int W = 224;
constexpr int HO = 112;
constexpr int WO = 112;
constexpr int GPR = WO / 8;            // 14 col-groups of 8 outputs
constexpr int PAIRS = HO / 2;          // 56 output-row pairs
constexpr int NC = 32 * 192;
constexpr int TOTAL = NC * PAIRS * GPR;  // 4,816,896 thread-iters
}

__global__ __launch_bounds__(256) void pool3x3s2_kernel(
    const float* __restrict__ X, float* __restrict__ Y) {
  const int stride = gridDim.x * blockDim.x;
  for (int idx = blockIdx.x * blockDim.x + threadIdx.x; idx < TOTAL;
       idx += stride) {
    const int g  = idx % GPR;          // col-group: outputs 8g..8g+7
    const int t  = idx / GPR;
    const int p  = t % PAIRS;          // row-pair: output rows 2p, 2p+1
    const int nc = t / PAIRS;

    const float* __restrict__ img = X + (size_t)nc * (H * W);
    const int ixs = 16 * g;            // input window x = [ixs-1, ixs+15]
    const int iy0 = 4 * p - 1;         // 5 input rows iy0..iy0+4; only iy=-1
                                       // (p==0, r==0) is ever out of bounds.

    float h[5][8];                     // per-row horizontal 3-tap maxes

#pragma unroll
    for (int r = 0; r < 5; ++r) {
      const int iy = iy0 + r;
      float a, x[16];
      if (iy >= 0) {                   // iy <= 223 always
        const float* __restrict__ row = img + iy * W + ixs;
        const float4 v0 = *reinterpret_cast<const float4*>(row);
        const float4 v1 = *reinterpret_cast<const float4*>(row + 4);
        const float4 v2 = *reinterpret_cast<const float4*>(row + 8);
        const float4 v3 = *reinterpret_cast<const float4*>(row + 12);
        a = (ixs > 0) ? row[-1] : 0.0f;   // pad fill 0.0 at x=-1
        x[0] = v0.x; x[1] = v0.y; x[2]  = v0.z; x[3]  = v0.w;
        x[4] = v1.x; x[5] = v1.y; x[6]  = v1.z; x[7]  = v1.w;
        x[8] = v2.x; x[9] = v2.y; x[10] = v2.z; x[11] = v2.w;
        x[12] = v3.x; x[13] = v3.y; x[14] = v3.z; x[15] = v3.w;
      } else {                         // whole row is padding -> fill 0.0
        a = 0.0f;
#pragma unroll
        for (int i = 0; i < 16; ++i) x[i] = 0.0f;
      }
      // output col j taps input x = 2j-1, 2j, 2j+1 (rel. to window base ixs)
      h[r][0] = fmaxf(fmaxf(a, x[0]), x[1]);
#pragma unroll
      for (int j = 1; j < 8; ++j)
        h[r][j] = fmaxf(fmaxf(x[2 * j - 1], x[2 * j]), x[2 * j + 1]);
    }

    float o0[8], o1[8];
#pragma unroll
    for (int j = 0; j < 8; ++j) {
      o0[j] = fmaxf(fmaxf(h[0][j], h[1][j]), h[2][j]);  // oy = 2p
      o1[j] = fmaxf(fmaxf(h[2][j], h[3][j]), h[4][j]);  // oy = 2p+1
    }

    float* __restrict__ out = Y + ((size_t)nc * HO + 2 * p) * WO + 8 * g;
    *reinterpret_cast<float4*>(out)          = make_float4(o0[0], o0[1], o0[2], o0[3]);
    *reinterpret_cast<float4*>(out + 4)      = make_float4(o0[4], o0[5], o0[6], o0[7]);
    *reinterpret_cast<float4*>(out + WO)     = make_float4(o1[0], o1[1], o1[2], o1[3]);
    *reinterpret_cast<float4*>(out + WO + 4) = make_float4(o1[4], o1[5], o1[6], o1[7]);
  }
}

extern "C" void kernel_launch(void* const* d_in, const int* in_sizes, int n_in,
                              void* d_out, int out_size, void* d_ws, size_t ws_size,
                              hipStream_t stream) {
  const float* X = (const float*)d_in[0];
  float* Y = (float*)d_out;
  pool3x3s2_kernel<<<2048, 256, 0, stream>>>(X, Y);
}